// Round 8
// baseline (193.927 us; speedup 1.0000x reference)
//
#include <hip/hip_runtime.h>
#include <math.h>

// Problem constants (B=16, C=3 -> 48 planes of 512x512)
#define H_IMG 512
#define W_IMG 512
#define HALO 5
#define WS11 11
#define NTHREADS 256
#define NCHUNK 16          // 16 chunks of 32 rows = 512 rows per block-column

// Rolling row buffer: 64 slots (circular, slot = (g+5) & 63), 5 fields.
// Layout [field][slot][col], row stride 36 floats (144 B, b128-aligned).
// Stage-B b32 reads: lanes 0..31 consecutive cols (bank perm), lanes 32..63
// slot+8 -> +32 banks = same pattern -> 2-way = free. Stage-A b128 writes:
// quad = (9*slot + c0/4) mod 8 -> balanced. (R5/R6-verified: 0 conflicts.)
#define SLOTS 64
#define RS 36
#define FS (SLOTS*RS)      // field stride: 2304 floats = 9216 B (imm offset ok)
#define RBUF_N (5*FS)      // 11520 floats = 46080 B -> 3 blocks/CU

typedef float f2 __attribute__((ext_vector_type(2)));

// Gaussian 11-tap, sigma=1.5, normalized; folds to literals after unroll.
__host__ __device__ constexpr float WT(int t) {
    return (t==0||t==10) ? 0.00102838f :
           (t==1||t==9)  ? 0.00759873f :
           (t==2||t==8)  ? 0.03600075f :
           (t==3||t==7)  ? 0.10936070f :
           (t==4||t==6)  ? 0.21300556f :
           (t==5)        ? 0.26601172f : 0.0f;
}

static __device__ __forceinline__ f2 splat2(float v) { f2 r = {v, v}; return r; }

// hconv of one input row-window (14 wide -> 4 outputs, 5 fields) + fused MSE.
// Writes to circular slot (g+5)&63. Zero rows (g outside image) write zeros.
static __device__ __forceinline__ void hconv_row(
        const float* __restrict__ xp, const float* __restrict__ yp,
        float* __restrict__ rbuf, int g, int c0, int bx, bool xin,
        float& mse_acc) {
    const bool rok = (unsigned)g < (unsigned)H_IMG;
    const int gc = bx*32 + c0 - 5;          // window start col (tap j=0)
    float xv[14], yv[14];
    if (rok && xin) {
        const int ga = gc - 3;              // 16B-aligned, in [24, 484]
        const float* rx = xp + (size_t)g*W_IMG + ga;
        const float* ry = yp + (size_t)g*W_IMG + ga;
        float4 XA = *(const float4*)(rx);
        float4 XB = *(const float4*)(rx + 4);
        float4 XC = *(const float4*)(rx + 8);
        float4 XD = *(const float4*)(rx + 12);
        float  XE = rx[16];
        float4 YA = *(const float4*)(ry);
        float4 YB = *(const float4*)(ry + 4);
        float4 YC = *(const float4*)(ry + 8);
        float4 YD = *(const float4*)(ry + 12);
        float  YE = ry[16];
        xv[0]=XA.w;  xv[1]=XB.x;  xv[2]=XB.y;  xv[3]=XB.z;  xv[4]=XB.w;
        xv[5]=XC.x;  xv[6]=XC.y;  xv[7]=XC.z;  xv[8]=XC.w;  xv[9]=XD.x;
        xv[10]=XD.y; xv[11]=XD.z; xv[12]=XD.w; xv[13]=XE;
        yv[0]=YA.w;  yv[1]=YB.x;  yv[2]=YB.y;  yv[3]=YB.z;  yv[4]=YB.w;
        yv[5]=YC.x;  yv[6]=YC.y;  yv[7]=YC.z;  yv[8]=YC.w;  yv[9]=YD.x;
        yv[10]=YD.y; yv[11]=YD.z; yv[12]=YD.w; yv[13]=YE;
    } else if (rok) {
        const float* prx = xp + (size_t)g*W_IMG + gc;
        const float* pry = yp + (size_t)g*W_IMG + gc;
#pragma unroll
        for (int j = 0; j < 14; ++j) {
            bool ok = (unsigned)(gc + j) < (unsigned)W_IMG;
            xv[j] = ok ? prx[j] : 0.f;
            yv[j] = ok ? pry[j] : 0.f;
        }
    } else {
#pragma unroll
        for (int j = 0; j < 14; ++j) { xv[j] = 0.f; yv[j] = 0.f; }
    }

    // fused MSE: this task's owned output cols are window j=5..8; every
    // in-image task row is owned exactly once (warmup rows 0..4, steady 5..511)
    if (rok) {
#pragma unroll
        for (int j = 5; j < 9; ++j) {
            float d = xv[j] - yv[j];
            mse_acc = fmaf(d, d, mse_acc);
        }
    }

    // Packed hconv: output pairs (k,k+1) in f2 -> v_pk_fma_f32.
    f2 A[5][2];
#pragma unroll
    for (int f = 0; f < 5; ++f) { A[f][0] = splat2(0.f); A[f][1] = splat2(0.f); }
#pragma unroll
    for (int j = 0; j < 14; ++j) {
        float px = xv[j], py = yv[j];
        f2 vp = {px, py};
        f2 vsq = vp * vp;                   // one pk_mul: (px^2, py^2)
        float pxy = px * py;
#pragma unroll
        for (int p = 0; p < 2; ++p) {
            const int t0 = j - 2*p;         // tap for k=2p; k=2p+1 uses t0-1
            if (t0 >= 0 && t0 <= WS11) {
                const f2 wp = {WT(t0), WT(t0-1)};
                A[0][p] = __builtin_elementwise_fma(wp, splat2(px),    A[0][p]);
                A[1][p] = __builtin_elementwise_fma(wp, splat2(py),    A[1][p]);
                A[2][p] = __builtin_elementwise_fma(wp, splat2(vsq.x), A[2][p]);
                A[3][p] = __builtin_elementwise_fma(wp, splat2(vsq.y), A[3][p]);
                A[4][p] = __builtin_elementwise_fma(wp, splat2(pxy),   A[4][p]);
            }
        }
    }
    const int slot = (g + 5) & (SLOTS-1);
    float* wb = &rbuf[slot*RS + c0];
#pragma unroll
    for (int f = 0; f < 5; ++f) {
        *(float4*)(wb + f*FS) =
            make_float4(A[f][0].x, A[f][0].y, A[f][1].x, A[f][1].y);
    }
}

__global__ __launch_bounds__(NTHREADS, 3) void ssim_stream(
        const float* __restrict__ cover, const float* __restrict__ wmed,
        float* __restrict__ part, int nParts) {
    __shared__ __align__(16) float rbuf[RBUF_N];   // 46080 B
    __shared__ float red[8];

    const int tid = threadIdx.x;
    const int bx = blockIdx.x & 15;         // column strip 0..15
    const int pl = blockIdx.x >> 4;         // plane 0..47
    const size_t pbase = (size_t)pl * (H_IMG*W_IMG);
    const float* xp = wmed + pbase;         // x = wmed, y = cover
    const float* yp = cover + pbase;
    const bool xin = (bx != 0) && (bx != 15);

    float ssim_acc = 0.f, mse_acc = 0.f;

    // Warmup: input rows g=-5..4 into slots 0..9 (80 tasks, one-time)
    if (tid < 80) {
        hconv_row(xp, yp, rbuf, (tid >> 3) - 5, (tid & 7) << 2, bx, xin, mse_acc);
    }
    __syncthreads();

    int kbase = 0;
#pragma clang loop unroll(disable)
    for (int k = 0; k < NCHUNK; ++k, kbase += 32) {
        // ---- Stage A: hconv 32 new rows, exactly one task per thread ----
        {
            const int r_local = tid >> 3;           // 0..31
            const int c0 = (tid & 7) << 2;          // 0,4,..,28
            hconv_row(xp, yp, rbuf, kbase + 5 + r_local, c0, bx, xin, mse_acc);
        }
        __syncthreads();

        // ---- Stage B: vconv + SSIM for output rows kbase..kbase+31;
        //      alternating wave pairs, 8 rows per thread ----
        if (((tid >> 7) & 1) == (k & 1)) {
            const int s  = tid & 127;
            const int c  = s & 31;
            const int r0 = (s >> 5) << 3;           // 0, 8, 16, 24
            // 18 circular slot indices, reused across the 5 fields
            int idx[18];
#pragma unroll
            for (int i = 0; i < 18; ++i) {
                int sl = (kbase + r0 + i) & (SLOTS-1);
                idx[i] = sl*RS + c;
            }
            f2 acc2[5][4];
#pragma unroll
            for (int f = 0; f < 5; ++f)
#pragma unroll
                for (int p = 0; p < 4; ++p) acc2[f][p] = splat2(0.f);
#pragma unroll
            for (int f = 0; f < 5; ++f) {
#pragma unroll
                for (int i = 0; i < 18; ++i) {
                    float v = rbuf[f*FS + idx[i]];
#pragma unroll
                    for (int p = 0; p < 4; ++p) {
                        const int t0 = i - 2*p;
                        if (t0 >= 0 && t0 <= WS11) {
                            const f2 wp = {WT(t0), WT(t0-1)};
                            acc2[f][p] = __builtin_elementwise_fma(wp, splat2(v), acc2[f][p]);
                        }
                    }
                }
            }
            const f2 c1 = {0.01f*0.01f, 0.01f*0.01f};
            const f2 c2 = {0.03f*0.03f, 0.03f*0.03f};
            const f2 two = {2.f, 2.f};
#pragma unroll
            for (int p = 0; p < 4; ++p) {
                f2 mx = acc2[0][p], my = acc2[1][p];
                f2 sxx = acc2[2][p] - mx*mx;
                f2 syy = acc2[3][p] - my*my;
                f2 sxy = acc2[4][p] - mx*my;
                f2 num = (two*mx*my + c1) * (two*sxy + c2);
                f2 den = (mx*mx + my*my + c1) * (sxx + syy + c2);
                ssim_acc += __fdividef(num.x, den.x) + __fdividef(num.y, den.y);
            }
        }
        __syncthreads();
    }

    // ---- Block reduce (4 waves of 64) ----
#pragma unroll
    for (int off = 32; off > 0; off >>= 1) {
        ssim_acc += __shfl_down(ssim_acc, off);
        mse_acc  += __shfl_down(mse_acc, off);
    }
    int wid = tid >> 6, lane = tid & 63;
    if (lane == 0) { red[wid] = ssim_acc; red[4+wid] = mse_acc; }
    __syncthreads();
    if (tid == 0) {
        float sv = red[0]+red[1]+red[2]+red[3];
        float m  = red[4]+red[5]+red[6]+red[7];
        part[blockIdx.x] = sv;
        part[nParts + blockIdx.x] = m;
    }
}

// 1024-thread finalize: vectorized partial reduce (double), fast-log BCE,
// curriculum weights.
#define FT 1024
__global__ __launch_bounds__(FT) void finalize_k(
        const float* __restrict__ part, int nParts,
        const float* __restrict__ wm_orig, const float* __restrict__ wm_ext,
        int nWm, const int* __restrict__ epoch_p,
        float* __restrict__ out, double inv_npix, double inv_nwm) {
    __shared__ double red[48];
    int tid = threadIdx.x;
    double s_ssim = 0.0, s_mse = 0.0, s_wl = 0.0;
    const float4* s4 = (const float4*)part;
    const float4* m4 = (const float4*)(part + nParts);
    int n4 = nParts >> 2;
    for (int i = tid; i < n4; i += FT) {
        float4 v = s4[i];
        s_ssim += (double)((v.x + v.y) + (v.z + v.w));
        float4 u = m4[i];
        s_mse  += (double)((u.x + u.y) + (u.z + u.w));
    }
    const float4* p4 = (const float4*)wm_orig;
    const float4* q4 = (const float4*)wm_ext;
    int w4 = nWm >> 2;
    for (int i = tid; i < w4; i += FT) {
        float4 p = p4[i], q = q4[i];
        float a;
        a  = -(p.x*__logf(q.x) + (1.f-p.x)*__logf(1.f-q.x));
        a += -(p.y*__logf(q.y) + (1.f-p.y)*__logf(1.f-q.y));
        a += -(p.z*__logf(q.z) + (1.f-p.z)*__logf(1.f-q.z));
        a += -(p.w*__logf(q.w) + (1.f-p.w)*__logf(1.f-q.w));
        s_wl += (double)a;
    }
#pragma unroll
    for (int off = 32; off > 0; off >>= 1) {
        s_ssim += __shfl_down(s_ssim, off);
        s_mse  += __shfl_down(s_mse, off);
        s_wl   += __shfl_down(s_wl, off);
    }
    int wid = tid >> 6, lane = tid & 63;
    if (lane == 0) { red[wid] = s_ssim; red[16+wid] = s_mse; red[32+wid] = s_wl; }
    __syncthreads();
    if (tid == 0) {
        double ssim_sum = 0.0, mse_sum = 0.0, wl_sum = 0.0;
        for (int i = 0; i < 16; ++i) {
            ssim_sum += red[i]; mse_sum += red[16+i]; wl_sum += red[32+i];
        }
        float sv = (float)(ssim_sum * inv_npix);
        float ml = (float)(mse_sum  * inv_npix);
        float wl = (float)(wl_sum   * inv_nwm);
        int e = *epoch_p;
        float w_img, w_ssim;
        if (e <= 12) {
            w_img = 0.05f; w_ssim = 0.05f;
        } else {
            float progress = fminf(1.0f, (float)(e - 12) / 10.0f);
            w_img  = 0.05f + (0.5f - 0.05f)*progress;
            w_ssim = 0.05f + (0.8f - 0.05f)*progress;
        }
        float sl = 1.0f - sv;
        float total = w_img*ml + w_ssim*sl + 3.0f*wl;
        out[0] = total;
        out[1] = ml;
        out[2] = sv;
        out[3] = wl;
    }
}

extern "C" void kernel_launch(void* const* d_in, const int* in_sizes, int n_in,
                              void* d_out, int out_size, void* d_ws, size_t ws_size,
                              hipStream_t stream) {
    const float* cover   = (const float*)d_in[0];
    const float* wmed    = (const float*)d_in[1];
    const float* wm_orig = (const float*)d_in[2];
    const float* wm_ext  = (const float*)d_in[3];
    const int*   epoch   = (const int*)d_in[4];
    float* out = (float*)d_out;

    int npix   = in_sizes[0];                 // 12,582,912
    int planes = npix / (H_IMG * W_IMG);      // 48
    int nWm    = in_sizes[2];                 // 16,384

    int nBlocks = 16 * planes;                // 768 = exactly 3 blocks/CU
    int nParts  = nBlocks;
    float* part = (float*)d_ws;               // 2 * nParts floats (6 KB)

    ssim_stream<<<nBlocks, NTHREADS, 0, stream>>>(cover, wmed, part, nParts);
    finalize_k<<<1, FT, 0, stream>>>(part, nParts, wm_orig, wm_ext, nWm,
                                     epoch, out,
                                     1.0 / (double)npix, 1.0 / (double)nWm);
}

// Round 9
// 181.972 us; speedup vs baseline: 1.0657x; 1.0657x over previous
//
#include <hip/hip_runtime.h>
#include <math.h>

// Problem constants (B=16, C=3 -> 48 planes of 512x512)
#define H_IMG 512
#define W_IMG 512
#define TH 32
#define TW 32
#define HALO 5
#define WS11 11
#define SH (TH + 2*HALO)   // 42 rows incl. halo
#define NTHREADS 256
#define TPB 4              // tiles per block (x-adjacent)

// rbuf layout: [field 0..4][row 0..41][col 0..31], row stride 36 floats.
// (R5/R6-verified: SQ_LDS_BANK_CONFLICT == 0.)
#define RS 36
#define RBUF_N (5*SH*RS)   // 7560 floats = 30240 B -> 5 blocks/CU fits 160K

typedef float f2 __attribute__((ext_vector_type(2)));

// Gaussian 11-tap, sigma=1.5, normalized; folds to literals after unroll.
__host__ __device__ constexpr float WT(int t) {
    return (t==0||t==10) ? 0.00102838f :
           (t==1||t==9)  ? 0.00759873f :
           (t==2||t==8)  ? 0.03600075f :
           (t==3||t==7)  ? 0.10936070f :
           (t==4||t==6)  ? 0.21300556f :
           (t==5)        ? 0.26601172f : 0.0f;
}

static __device__ __forceinline__ f2 splat2(float v) { f2 r = {v, v}; return r; }

__global__ __launch_bounds__(NTHREADS, 5) void ssim_mse_tile(
        const float* __restrict__ cover, const float* __restrict__ wmed,
        float* __restrict__ part, int nParts) {
    __shared__ __align__(16) float rbuf[RBUF_N];   // 30240 B
    __shared__ float red[8];

    const int tid = threadIdx.x;
    float ssim_acc = 0.f, mse_acc = 0.f;

    for (int it = 0; it < TPB; ++it) {
        const int tile = blockIdx.x * TPB + it;
        const int bx = tile & 15;
        const int by = (tile >> 4) & 15;
        const int pl = tile >> 8;
        const size_t pbase = (size_t)pl * (H_IMG*W_IMG);
        const float* xp = wmed + pbase;   // x = wmed, y = cover
        const float* yp = cover + pbase;
        const int ty0 = by*TH - HALO;
        const int tx0 = bx*TW - HALO;
        const bool xin = (bx != 0) && (bx != 15);   // fast-path columns

        // ---- Stage A: horizontal 11-tap conv of 5 fields, from global ----
        // 42 rows x 8 col-groups = 336 tasks; 4 outputs from 14-wide window.
        for (int t = tid; t < SH*8; t += NTHREADS) {
            const int r = t >> 3, c0 = (t & 7) << 2;
            const int gy = ty0 + r;
            const bool rok = (unsigned)gy < (unsigned)H_IMG;
            float xv[14], yv[14];
            if (rok && xin) {
                // ga = tx0+c0-3 == bx*32+c0-8 : 16B-aligned, in [24, 484]
                const int ga = tx0 + c0 - 3;
                const float* rx = xp + (size_t)gy*W_IMG + ga;
                const float* ry = yp + (size_t)gy*W_IMG + ga;
                float4 XA = *(const float4*)(rx);
                float4 XB = *(const float4*)(rx + 4);
                float4 XC = *(const float4*)(rx + 8);
                float4 XD = *(const float4*)(rx + 12);
                float  XE = rx[16];
                float4 YA = *(const float4*)(ry);
                float4 YB = *(const float4*)(ry + 4);
                float4 YC = *(const float4*)(ry + 8);
                float4 YD = *(const float4*)(ry + 12);
                float  YE = ry[16];
                xv[0]=XA.w;  xv[1]=XB.x;  xv[2]=XB.y;  xv[3]=XB.z;  xv[4]=XB.w;
                xv[5]=XC.x;  xv[6]=XC.y;  xv[7]=XC.z;  xv[8]=XC.w;  xv[9]=XD.x;
                xv[10]=XD.y; xv[11]=XD.z; xv[12]=XD.w; xv[13]=XE;
                yv[0]=YA.w;  yv[1]=YB.x;  yv[2]=YB.y;  yv[3]=YB.z;  yv[4]=YB.w;
                yv[5]=YC.x;  yv[6]=YC.y;  yv[7]=YC.z;  yv[8]=YC.w;  yv[9]=YD.x;
                yv[10]=YD.y; yv[11]=YD.z; yv[12]=YD.w; yv[13]=YE;
            } else if (rok) {
                const int gc = tx0 + c0;
                const float* prx = xp + (size_t)gy*W_IMG + gc;
                const float* pry = yp + (size_t)gy*W_IMG + gc;
#pragma unroll
                for (int j = 0; j < 14; ++j) {
                    bool ok = (unsigned)(gc + j) < (unsigned)W_IMG;
                    xv[j] = ok ? prx[j] : 0.f;
                    yv[j] = ok ? pry[j] : 0.f;
                }
            } else {
#pragma unroll
                for (int j = 0; j < 14; ++j) { xv[j] = 0.f; yv[j] = 0.f; }
            }

            // fused MSE: interior pixels are window j=5..8, rows 5..36
            if (rok && r >= HALO && r < HALO+TH) {
#pragma unroll
                for (int j = 5; j < 9; ++j) {
                    float d = xv[j] - yv[j];
                    mse_acc = fmaf(d, d, mse_acc);
                }
            }

            // Packed hconv: accumulator pairs (k,k+1) in f2 -> v_pk_fma_f32.
            f2 A[5][2];
#pragma unroll
            for (int f = 0; f < 5; ++f) { A[f][0] = splat2(0.f); A[f][1] = splat2(0.f); }
#pragma unroll
            for (int j = 0; j < 14; ++j) {
                float px = xv[j], py = yv[j];
                f2 vp = {px, py};
                f2 vsq = vp * vp;               // one pk_mul: (px^2, py^2)
                float pxy = px * py;
#pragma unroll
                for (int p = 0; p < 2; ++p) {
                    const int t0 = j - 2*p;      // tap for k=2p; k=2p+1 uses t0-1
                    if (t0 >= 0 && t0 <= WS11) {
                        const f2 wp = {WT(t0), WT(t0-1)};
                        A[0][p] = __builtin_elementwise_fma(wp, splat2(px),    A[0][p]);
                        A[1][p] = __builtin_elementwise_fma(wp, splat2(py),    A[1][p]);
                        A[2][p] = __builtin_elementwise_fma(wp, splat2(vsq.x), A[2][p]);
                        A[3][p] = __builtin_elementwise_fma(wp, splat2(vsq.y), A[3][p]);
                        A[4][p] = __builtin_elementwise_fma(wp, splat2(pxy),   A[4][p]);
                    }
                }
            }
            float* wb = &rbuf[r*RS + c0];
#pragma unroll
            for (int f = 0; f < 5; ++f) {
                *(float4*)(wb + f*SH*RS) =
                    make_float4(A[f][0].x, A[f][0].y, A[f][1].x, A[f][1].y);
            }
        }
        __syncthreads();

        // ---- Stage B: vertical 11-tap conv + SSIM; 8 rows per thread,
        //      128 active threads; alternate wave-pairs across tiles. ----
        if (((tid >> 7) & 1) == (it & 1)) {
            const f2 c1 = {0.01f*0.01f, 0.01f*0.01f};
            const f2 c2 = {0.03f*0.03f, 0.03f*0.03f};
            const f2 two = {2.f, 2.f};
            const int s  = tid & 127;
            const int c  = s & 31;
            const int r0 = (s >> 5) << 3;    // 0, 8, 16, 24
            f2 acc2[5][4];
#pragma unroll
            for (int f = 0; f < 5; ++f)
#pragma unroll
                for (int p = 0; p < 4; ++p) acc2[f][p] = splat2(0.f);
#pragma unroll
            for (int f = 0; f < 5; ++f) {
                const float* rb = &rbuf[f*SH*RS + r0*RS + c];
#pragma unroll
                for (int i = 0; i < 18; ++i) {
                    float v = rb[i*RS];
#pragma unroll
                    for (int p = 0; p < 4; ++p) {
                        const int t0 = i - 2*p;
                        if (t0 >= 0 && t0 <= WS11) {
                            const f2 wp = {WT(t0), WT(t0-1)};
                            acc2[f][p] = __builtin_elementwise_fma(wp, splat2(v), acc2[f][p]);
                        }
                    }
                }
            }
#pragma unroll
            for (int p = 0; p < 4; ++p) {
                f2 mx = acc2[0][p], my = acc2[1][p];
                f2 sxx = acc2[2][p] - mx*mx;
                f2 syy = acc2[3][p] - my*my;
                f2 sxy = acc2[4][p] - mx*my;
                f2 num = (two*mx*my + c1) * (two*sxy + c2);
                f2 den = (mx*mx + my*my + c1) * (sxx + syy + c2);
                ssim_acc += __fdividef(num.x, den.x) + __fdividef(num.y, den.y);
            }
        }
        __syncthreads();   // rbuf reused by next tile
    }

    // ---- Block reduce (4 waves of 64) ----
#pragma unroll
    for (int off = 32; off > 0; off >>= 1) {
        ssim_acc += __shfl_down(ssim_acc, off);
        mse_acc  += __shfl_down(mse_acc, off);
    }
    int wid = tid >> 6, lane = tid & 63;
    if (lane == 0) { red[wid] = ssim_acc; red[4+wid] = mse_acc; }
    __syncthreads();
    if (tid == 0) {
        float s = red[0]+red[1]+red[2]+red[3];
        float m = red[4]+red[5]+red[6]+red[7];
        part[blockIdx.x] = s;
        part[nParts + blockIdx.x] = m;
    }
}

// 1024-thread finalize: vectorized partial reduce (double), fast-log BCE,
// curriculum weights.
#define FT 1024
__global__ __launch_bounds__(FT) void finalize_k(
        const float* __restrict__ part, int nParts,
        const float* __restrict__ wm_orig, const float* __restrict__ wm_ext,
        int nWm, const int* __restrict__ epoch_p,
        float* __restrict__ out, double inv_npix, double inv_nwm) {
    __shared__ double red[48];
    int tid = threadIdx.x;
    double s_ssim = 0.0, s_mse = 0.0, s_wl = 0.0;
    const float4* s4 = (const float4*)part;
    const float4* m4 = (const float4*)(part + nParts);
    int n4 = nParts >> 2;
    for (int i = tid; i < n4; i += FT) {
        float4 v = s4[i];
        s_ssim += (double)((v.x + v.y) + (v.z + v.w));
        float4 u = m4[i];
        s_mse  += (double)((u.x + u.y) + (u.z + u.w));
    }
    const float4* p4 = (const float4*)wm_orig;
    const float4* q4 = (const float4*)wm_ext;
    int w4 = nWm >> 2;
    for (int i = tid; i < w4; i += FT) {
        float4 p = p4[i], q = q4[i];
        float a;
        a  = -(p.x*__logf(q.x) + (1.f-p.x)*__logf(1.f-q.x));
        a += -(p.y*__logf(q.y) + (1.f-p.y)*__logf(1.f-q.y));
        a += -(p.z*__logf(q.z) + (1.f-p.z)*__logf(1.f-q.z));
        a += -(p.w*__logf(q.w) + (1.f-p.w)*__logf(1.f-q.w));
        s_wl += (double)a;
    }
#pragma unroll
    for (int off = 32; off > 0; off >>= 1) {
        s_ssim += __shfl_down(s_ssim, off);
        s_mse  += __shfl_down(s_mse, off);
        s_wl   += __shfl_down(s_wl, off);
    }
    int wid = tid >> 6, lane = tid & 63;
    if (lane == 0) { red[wid] = s_ssim; red[16+wid] = s_mse; red[32+wid] = s_wl; }
    __syncthreads();
    if (tid == 0) {
        double ssim_sum = 0.0, mse_sum = 0.0, wl_sum = 0.0;
        for (int i = 0; i < 16; ++i) {
            ssim_sum += red[i]; mse_sum += red[16+i]; wl_sum += red[32+i];
        }
        float sv = (float)(ssim_sum * inv_npix);
        float ml = (float)(mse_sum  * inv_npix);
        float wl = (float)(wl_sum   * inv_nwm);
        int e = *epoch_p;
        float w_img, w_ssim;
        if (e <= 12) {
            w_img = 0.05f; w_ssim = 0.05f;
        } else {
            float progress = fminf(1.0f, (float)(e - 12) / 10.0f);
            w_img  = 0.05f + (0.5f - 0.05f)*progress;
            w_ssim = 0.05f + (0.8f - 0.05f)*progress;
        }
        float sl = 1.0f - sv;
        float total = w_img*ml + w_ssim*sl + 3.0f*wl;
        out[0] = total;
        out[1] = ml;
        out[2] = sv;
        out[3] = wl;
    }
}

extern "C" void kernel_launch(void* const* d_in, const int* in_sizes, int n_in,
                              void* d_out, int out_size, void* d_ws, size_t ws_size,
                              hipStream_t stream) {
    const float* cover   = (const float*)d_in[0];
    const float* wmed    = (const float*)d_in[1];
    const float* wm_orig = (const float*)d_in[2];
    const float* wm_ext  = (const float*)d_in[3];
    const int*   epoch   = (const int*)d_in[4];
    float* out = (float*)d_out;

    int npix   = in_sizes[0];                 // 12,582,912
    int planes = npix / (H_IMG * W_IMG);      // 48
    int nWm    = in_sizes[2];                 // 16,384

    int nTiles  = 16 * 16 * planes;           // 12288
    int nBlocks = nTiles / TPB;               // 3072 blocks, 4 x-adjacent tiles
    int nParts  = nBlocks;
    float* part = (float*)d_ws;               // 2 * nParts floats (24 KB)

    ssim_mse_tile<<<nBlocks, NTHREADS, 0, stream>>>(cover, wmed, part, nParts);
    finalize_k<<<1, FT, 0, stream>>>(part, nParts, wm_orig, wm_ext, nWm,
                                     epoch, out,
                                     1.0 / (double)npix, 1.0 / (double)nWm);
}